// Round 14
// baseline (153.798 us; speedup 1.0000x reference)
//
#include <hip/hip_runtime.h>
#include <hip/hip_bf16.h>
#include <stdint.h>

// ---------------------------------------------------------------------------
// TensorNet: fused encoder MLP (128->256->256->256, relu) over 32x4096 tokens,
// per-batch mean -> p = relu(m^2) -> decoder MLP (256->512->512->10).
//
// R29 (final probe): LDS 33792 -> 32768 exactly. Epilogue scratch moves
// from a 17-float4-padded region spilling 1KB past Hs1 into Hs1's 16KB with
// an XOR slot layout (slot = l ^ (row&15); bank = ((l^row)&15)*4+r is
// bijective over the wave -> 2-way = free). R17 measured a residency step
// at exactly 32768; this tests whether the 32KB boundary still matters.
// Everything else byte-identical to R28 (best: 150.8us; encoder 48.4 avg,
// VGPR 52, conflicts 2.62M).
//
// PRE-COMMITMENT: if |delta total| <= 1us, next round declares structural
// convergence (encoder ~47us serial-chain floor: 3-layer fused chain, 4
// barriers, no pipe >50%, all levers measured: occupancy null R23, bank
// conflicts fixed R24, DS-shuffles removed R25, a-load stalls hidden R27,
// pack coalesced R28, decoder split R26).
//
// HARD RULES from the log:
//  - NEVER pass a min-waves arg to __launch_bounds__ (R5, R19, R22: spills).
//  - NEVER grow per-wave a-load count for "sharing" (R18: 185us).
//  - NEVER shrink MTILE / grow encoder block count (R20).
// ---------------------------------------------------------------------------

#define NIN   128
#define NHID  256
#define NDEC  512
#define NOUTC 10
#define BATCH 32
#define NTOK  4096
#define MTILE 64
#define NBLK  (BATCH * (NTOK / MTILE))   // 2048 encoder tiles

#define SW2(t) (((t) & 15) << 4)         // XOR swizzle, byte bits 4-7

typedef short bf16x8 __attribute__((ext_vector_type(8)));
typedef float floatx4 __attribute__((ext_vector_type(4)));
typedef long  longx2  __attribute__((ext_vector_type(2)));

__device__ __forceinline__ uint16_t f2b(float f) {
  union { uint32_t u; float f; } v; v.f = f;
  uint32_t r = v.u + 0x7FFFu + ((v.u >> 16) & 1u);   // RNE
  return (uint16_t)(r >> 16);
}
__device__ __forceinline__ uint32_t pkbf(float lo, float hi) {
  __hip_bfloat162 h = __float22bfloat162_rn(float2{lo, hi});  // v_cvt_pk_bf16_f32
  union { __hip_bfloat162 h; uint32_t u; } c; c.h = h;
  return c.u;
}

// ---------------------------------------------------------------------------
// Pack weights, read-coalesced (R28): thread p reads W?[p] linearly, computes
// the fragment-order destination, scattered-writes. Also zero-inits msum and
// pre-loads out with c3 (decoder atomics accumulate; stream-ordered).
// ---------------------------------------------------------------------------
__global__ __launch_bounds__(256) void pack_weights(
    const float* __restrict__ W1, const float* __restrict__ W2,
    const float* __restrict__ W3, const float* __restrict__ c3,
    uint8_t* __restrict__ pW, float* __restrict__ msum,
    float* __restrict__ out) {
  int p = blockIdx.x * blockDim.x + threadIdx.x;
  if (p < BATCH * NHID) msum[p] = 0.f;
  if (p < BATCH * NOUTC) out[p] = c3[p % NOUTC];
  if (p < 32768) {
    // W1: [128][256] row-major; p = k*256 + m. bf16, kc-major frags.
    int k = p >> 8, m = p & 255;
    int mt = m >> 4, l15 = m & 15;
    int kc = k >> 5, kk = k & 31;
    int ln = ((kk >> 3) << 4) + l15;
    int j  = kk & 7;
    ((uint16_t*)pW)[(((mt * 4 + kc) * 64 + ln) << 3) + j] = f2b(W1[p]);
  } else {
    int p2 = p - 32768;
    const float* W = (p2 < 65536) ? W2 : W3;
    int base = (p2 < 65536) ? 65536 : 131072;
    if (p2 >= 65536) p2 -= 65536;
    // W2/W3: [256][256] row-major; p2 = k*256 + m. fp8 e4m3, frag-major.
    int k = p2 >> 8, m = p2 & 255;
    int mt = m >> 4, l15 = m & 15;
    int kc = k >> 5, kk = k & 31;
    int ln = ((kk >> 3) << 4) + l15;
    int j  = kk & 7;
    int r = __builtin_amdgcn_cvt_pk_fp8_f32(W[p2], 0.f, 0, false);
    pW[base + (mt * 64 + ln) * 64 + kc * 8 + j] = (uint8_t)(r & 0xFF);
  }
}

// ---------------------------------------------------------------------------
// Fused encoder. Block = 512 thr (8 waves), 64 tokens. Wave w owns hidden
// rows [32w,32w+32). HsAll: [0,16K) x tile then h2; [16K,32K) h1, reused as
// epilogue scratch (XOR slot layout). 32768 B exactly. 4 barriers.
// a-frags prefetched across each barrier + pipelined one kc ahead;
// setprio(1) around MFMA groups.
// ---------------------------------------------------------------------------
__global__ __launch_bounds__(512) void encoder(
    const float* __restrict__ x,        // [BATCH*NTOK][NIN] fp32
    const uint8_t* __restrict__ pW,
    const float* __restrict__ b1,
    const float* __restrict__ b2,
    const float* __restrict__ b3,
    float* __restrict__ msum) {         // [BATCH][NHID] fp32 accum
  __shared__ __align__(16) uint8_t HsAll[32768];
  uint8_t* Hs0 = HsAll;                 // 16384 B: x (bf16), then h2 (fp8)
  uint8_t* Hs1 = HsAll + 16384;         // 16384 B: h1 (fp8), then scratch

  const int tid  = threadIdx.x;
  const int wave = tid >> 6;
  const int lane = tid & 63;
  const int l15  = lane & 15;
  const int q    = lane >> 4;
  const int tok0  = blockIdx.x * MTILE;
  const int batch = blockIdx.x >> 6;          // 64 tiles per batch

  const uint16_t* pW1 = (const uint16_t*)pW;  // bf16 frags, KC=4
  const uint8_t*  pW2 = pW + 65536;           // fp8 frags, fragment-major
  const uint8_t*  pW3 = pW + 131072;          // fp8 frags, fragment-major

  // ---- stage x tile: 64 tok x 128 ch fp32 -> bf16, row 256B, SW2 ----
  {
    const float4* xv = (const float4*)(x + (size_t)tok0 * NIN);
#pragma unroll
    for (int i = 0; i < 2; ++i) {
      const int u = tid + i * 512;            // 8-float unit, 0..1023
      float4 va = xv[2 * u];
      float4 vb = xv[2 * u + 1];
      uint4 w = make_uint4(pkbf(va.x, va.y), pkbf(va.z, va.w),
                           pkbf(vb.x, vb.y), pkbf(vb.z, vb.w));
      const int row = u >> 4;                 // token 0..63
      const int cb  = (u & 15) << 4;          // byte col 0..240
      *(uint4*)&Hs0[row * 256 + (cb ^ SW2(row))] = w;
    }
  }
  // prefetch L1 kc=0 a-frags before the barrier (pW-only dependency)
  bf16x8 a0 = *(const bf16x8*)(pW1 + ((((wave * 2 + 0) * 4 + 0) * 64 + lane) << 3));
  bf16x8 a1 = *(const bf16x8*)(pW1 + ((((wave * 2 + 1) * 4 + 0) * 64 + lane) << 3));
  __syncthreads();   // (1) x staged

  floatx4 acc[2][4];   // [jt][tt]

  // ---- layer 1: K = 128 bf16, A = W1^T, B = x(Hs0); acc init = bias ----
#pragma unroll
  for (int jt = 0; jt < 2; ++jt) {
    const float4 bb = *(const float4*)&b1[(wave * 2 + jt) * 16 + q * 4];
#pragma unroll
    for (int tt = 0; tt < 4; ++tt)
      acc[jt][tt] = (floatx4){bb.x, bb.y, bb.z, bb.w};
  }
#pragma unroll
  for (int kc = 0; kc < 4; ++kc) {
    bf16x8 na0, na1;
    if (kc < 3) {
      na0 = *(const bf16x8*)(pW1 + ((((wave * 2 + 0) * 4 + kc + 1) * 64 + lane) << 3));
      na1 = *(const bf16x8*)(pW1 + ((((wave * 2 + 1) * 4 + kc + 1) * 64 + lane) << 3));
    }
    bf16x8 b[4];
#pragma unroll
    for (int tt = 0; tt < 4; ++tt) {
      const int t = tt * 16 + l15;
      b[tt] = *(const bf16x8*)&Hs0[t * 256 + ((kc * 64 + q * 16) ^ SW2(t))];
    }
    __builtin_amdgcn_s_setprio(1);
#pragma unroll
    for (int tt = 0; tt < 4; ++tt) {
      acc[0][tt] = __builtin_amdgcn_mfma_f32_16x16x32_bf16(a0, b[tt], acc[0][tt], 0, 0, 0);
      acc[1][tt] = __builtin_amdgcn_mfma_f32_16x16x32_bf16(a1, b[tt], acc[1][tt], 0, 0, 0);
    }
    __builtin_amdgcn_s_setprio(0);
    if (kc < 3) { a0 = na0; a1 = na1; }
  }
  // h1 -> Hs1 (fragment-major fp8); no barrier needed (different buffer)
#pragma unroll
  for (int jt = 0; jt < 2; ++jt) {
    const int j0 = (wave * 2 + jt) * 16 + q * 4;
    const int pb = ((j0 >> 3) & 3) * 64 + (j0 >> 5) * 8 + (j0 & 7);
#pragma unroll
    for (int tt = 0; tt < 4; ++tt) {
      const int t = tt * 16 + l15;
      float v0 = fmaxf(acc[jt][tt][0], 0.f);
      float v1 = fmaxf(acc[jt][tt][1], 0.f);
      float v2 = fmaxf(acc[jt][tt][2], 0.f);
      float v3 = fmaxf(acc[jt][tt][3], 0.f);
      int u = __builtin_amdgcn_cvt_pk_fp8_f32(v0, v1, 0, false);
      u = __builtin_amdgcn_cvt_pk_fp8_f32(v2, v3, u, true);
      *(uint32_t*)&Hs1[t * 256 + (pb ^ SW2(t))] = (uint32_t)u;
    }
  }
  // prefetch L2 kc2=0 a-frags before the barrier
  longx2 A0 = *(const longx2*)(pW2 + ((wave * 2 + 0) * 64 + lane) * 64);
  longx2 A1 = *(const longx2*)(pW2 + ((wave * 2 + 1) * 64 + lane) * 64);
  __syncthreads();   // (2) h1 complete (implies all x reads done too)

  // ---- layer 2: K = 256 fp8, A = W2^T (fragment-major), B = h1(Hs1) ----
#pragma unroll
  for (int jt = 0; jt < 2; ++jt) {
    const float4 bb = *(const float4*)&b2[(wave * 2 + jt) * 16 + q * 4];
#pragma unroll
    for (int tt = 0; tt < 4; ++tt)
      acc[jt][tt] = (floatx4){bb.x, bb.y, bb.z, bb.w};
  }
#pragma unroll
  for (int kc2 = 0; kc2 < 4; ++kc2) {
    longx2 nA0, nA1;
    if (kc2 < 3) {
      nA0 = *(const longx2*)(pW2 + ((wave * 2 + 0) * 64 + lane) * 64 + (kc2 + 1) * 16);
      nA1 = *(const longx2*)(pW2 + ((wave * 2 + 1) * 64 + lane) * 64 + (kc2 + 1) * 16);
    }
    longx2 b[4];
#pragma unroll
    for (int tt = 0; tt < 4; ++tt) {
      const int t = tt * 16 + l15;
      b[tt] = *(const longx2*)&Hs1[t * 256 + ((q * 64 + kc2 * 16) ^ SW2(t))];
    }
    __builtin_amdgcn_s_setprio(1);
#pragma unroll
    for (int s = 0; s < 2; ++s) {
#pragma unroll
      for (int tt = 0; tt < 4; ++tt) {
        acc[0][tt] = __builtin_amdgcn_mfma_f32_16x16x32_fp8_fp8(A0[s], b[tt][s], acc[0][tt], 0, 0, 0);
        acc[1][tt] = __builtin_amdgcn_mfma_f32_16x16x32_fp8_fp8(A1[s], b[tt][s], acc[1][tt], 0, 0, 0);
      }
    }
    __builtin_amdgcn_s_setprio(0);
    if (kc2 < 3) { A0 = nA0; A1 = nA1; }
  }
  // h2 -> Hs0 (x is dead: barrier (2) proved all x reads finished)
#pragma unroll
  for (int jt = 0; jt < 2; ++jt) {
    const int j0 = (wave * 2 + jt) * 16 + q * 4;
    const int pb = ((j0 >> 3) & 3) * 64 + (j0 >> 5) * 8 + (j0 & 7);
#pragma unroll
    for (int tt = 0; tt < 4; ++tt) {
      const int t = tt * 16 + l15;
      float v0 = fmaxf(acc[jt][tt][0], 0.f);
      float v1 = fmaxf(acc[jt][tt][1], 0.f);
      float v2 = fmaxf(acc[jt][tt][2], 0.f);
      float v3 = fmaxf(acc[jt][tt][3], 0.f);
      int u = __builtin_amdgcn_cvt_pk_fp8_f32(v0, v1, 0, false);
      u = __builtin_amdgcn_cvt_pk_fp8_f32(v2, v3, u, true);
      *(uint32_t*)&Hs0[t * 256 + (pb ^ SW2(t))] = (uint32_t)u;
    }
  }
  // prefetch L3 kc2=0 a-frags before the barrier
  longx2 C0 = *(const longx2*)(pW3 + ((wave * 2 + 0) * 64 + lane) * 64);
  longx2 C1 = *(const longx2*)(pW3 + ((wave * 2 + 1) * 64 + lane) * 64);
  __syncthreads();   // (3) h2 complete (implies all h1 reads done -> Hs1 dead)

  // ---- layer 3: K = 256 fp8, A = W3^T (fragment-major), B = h2(Hs0) ----
#pragma unroll
  for (int jt = 0; jt < 2; ++jt) {
    const float4 bb = *(const float4*)&b3[(wave * 2 + jt) * 16 + q * 4];
#pragma unroll
    for (int tt = 0; tt < 4; ++tt)
      acc[jt][tt] = (floatx4){bb.x, bb.y, bb.z, bb.w};
  }
#pragma unroll
  for (int kc2 = 0; kc2 < 4; ++kc2) {
    longx2 nC0, nC1;
    if (kc2 < 3) {
      nC0 = *(const longx2*)(pW3 + ((wave * 2 + 0) * 64 + lane) * 64 + (kc2 + 1) * 16);
      nC1 = *(const longx2*)(pW3 + ((wave * 2 + 1) * 64 + lane) * 64 + (kc2 + 1) * 16);
    }
    longx2 b[4];
#pragma unroll
    for (int tt = 0; tt < 4; ++tt) {
      const int t = tt * 16 + l15;
      b[tt] = *(const longx2*)&Hs0[t * 256 + ((q * 64 + kc2 * 16) ^ SW2(t))];
    }
    __builtin_amdgcn_s_setprio(1);
#pragma unroll
    for (int s = 0; s < 2; ++s) {
#pragma unroll
      for (int tt = 0; tt < 4; ++tt) {
        acc[0][tt] = __builtin_amdgcn_mfma_f32_16x16x32_fp8_fp8(C0[s], b[tt][s], acc[0][tt], 0, 0, 0);
        acc[1][tt] = __builtin_amdgcn_mfma_f32_16x16x32_fp8_fp8(C1[s], b[tt][s], acc[1][tt], 0, 0, 0);
      }
    }
    __builtin_amdgcn_s_setprio(0);
    if (kc2 < 3) { C0 = nC0; C1 = nC1; }
  }

  // relu + token-sum epilogue, scratch in Hs1 (dead since barrier (3)),
  // XOR slot layout: row = (wave*2+jt)*4+q (0..63), slot = l15 ^ (row&15).
  // Bank check (read, fixed l): ((l^row)&15)*4 + r bijective over the wave
  // -> 2-way, free. Fits 16KB exactly -> LDS 32768 total.
#pragma unroll
  for (int jt = 0; jt < 2; ++jt) {
    float s0 = 0.f, s1 = 0.f, s2 = 0.f, s3 = 0.f;
#pragma unroll
    for (int tt = 0; tt < 4; ++tt) {
      s0 += fmaxf(acc[jt][tt][0], 0.f);
      s1 += fmaxf(acc[jt][tt][1], 0.f);
      s2 += fmaxf(acc[jt][tt][2], 0.f);
      s3 += fmaxf(acc[jt][tt][3], 0.f);
    }
    const int row = (wave * 2 + jt) * 4 + q;
    *(float4*)&Hs1[row * 256 + ((l15 ^ (row & 15)) << 4)] = (float4){s0, s1, s2, s3};
  }
  __syncthreads();   // (4) scratch ready
  if (tid < NHID) {
    // hidden j = tid: row = (j>>4)*4 + ((j>>2)&3), elem r = j&3
    const int row = ((tid >> 4) << 2) + ((tid >> 2) & 3);
    const int r = tid & 3;
    float v = 0.f;
#pragma unroll
    for (int l = 0; l < 16; ++l)
      v += *(const float*)&Hs1[row * 256 + (((l ^ (row & 15)) << 4)) + r * 4];
    atomicAdd(&msum[batch * NHID + tid], v);
  }
}

// ---------------------------------------------------------------------------
// Decoder: 256 blocks = (batch x d2-eighth), 1024 threads. Each block
// computes the full d1 (redundant x8, D1 is L2-resident), its 64-wide d2
// eighth, and atomicAdds its partial L3 dot into out (pre-init'd to c3).
// (BYTE-IDENTICAL TO R26.)
// ---------------------------------------------------------------------------
__global__ __launch_bounds__(1024) void decoder(
    const float* __restrict__ msum,
    const float* __restrict__ D1, const float* __restrict__ c1,
    const float* __restrict__ D2, const float* __restrict__ c2,
    const float* __restrict__ D3,
    float* __restrict__ out) {
  __shared__ float p[NHID];
  __shared__ float d1[NDEC];
  __shared__ float d2e[64];
  __shared__ __align__(16) float red[4096];   // 16 KB
  const int b = blockIdx.x >> 3, qd = blockIdx.x & 7, t = threadIdx.x;

  if (t < NHID) {
    float m = msum[b * NHID + t] * (1.f / NTOK);
    p[t] = m * m;                        // relu(m^2) == m^2
  }
  __syncthreads();

  // ---- layer 1 (full, redundant x8): K = 256 -> 32 k per split ----
  {
    const int jg = t & 127;              // j-group of 4
    const int ks = t >> 7;               // 0..7 K-split
    const float4* D1v = (const float4*)D1;   // [256][128] float4
    float4 s = {0.f, 0.f, 0.f, 0.f};
    for (int k = ks * 32; k < ks * 32 + 32; ++k) {
      float4 w = D1v[k * 128 + jg];
      float pv = p[k];
      s.x += pv * w.x; s.y += pv * w.y; s.z += pv * w.z; s.w += pv * w.w;
    }
    *(float4*)&red[t * 4] = s;
    __syncthreads();
    if (t < NDEC) {
      float v = c1[t];
#pragma unroll
      for (int i = 0; i < 8; ++i) v += red[i * 512 + t];
      d1[t] = fmaxf(v, 0.f);
    }
    __syncthreads();
  }

  // ---- layer 2 (eighth): 64 outs, K = 512 -> 64 splits x 8 k ----
  {
    const int jg2 = t & 15;              // float4 group within eighth
    const int ks2 = t >> 4;              // 0..63 K-split
    const float4* D2v = (const float4*)D2;   // [512][128] float4
    float4 s = {0.f, 0.f, 0.f, 0.f};
    for (int k = ks2 * 8; k < ks2 * 8 + 8; ++k) {
      float4 w = D2v[k * 128 + qd * 16 + jg2];
      float hv = d1[k];
      s.x += hv * w.x; s.y += hv * w.y; s.z += hv * w.z; s.w += hv * w.w;
    }
    *(float4*)&red[t * 4] = s;           // == red[ks2*64 + jg2*4 + c]
    __syncthreads();
    if (t < 64) {
      float v = c2[qd * 64 + t];
#pragma unroll
      for (int i = 0; i < 64; ++i) v += red[i * 64 + t];
      d2e[t] = fmaxf(v, 0.f);
    }
    __syncthreads();
  }

  // ---- layer 3 partial: eighth K = 64; 64 k-chunks x 16 j-slots ----
  {
    const int j3 = t & 15;
    const int kc = t >> 4;               // 0..63, 1 k each
    float s = 0.f;
    if (j3 < NOUTC)
      s = d2e[kc] * D3[(qd * 64 + kc) * NOUTC + j3];
    red[t] = s;
    __syncthreads();
    if (t < NOUTC) {
      float v = 0.f;
#pragma unroll
      for (int i = 0; i < 64; ++i) v += red[i * 16 + t];
      atomicAdd(&out[b * NOUTC + t], v);
    }
  }
}

// ---------------------------------------------------------------------------
extern "C" void kernel_launch(void* const* d_in, const int* in_sizes, int n_in,
                              void* d_out, int out_size, void* d_ws, size_t ws_size,
                              hipStream_t stream) {
  const float* x  = (const float*)d_in[0];
  const float* W1 = (const float*)d_in[1];
  const float* b1 = (const float*)d_in[2];
  const float* W2 = (const float*)d_in[3];
  const float* b2 = (const float*)d_in[4];
  const float* W3 = (const float*)d_in[5];
  const float* b3 = (const float*)d_in[6];
  const float* D1 = (const float*)d_in[7];
  const float* c1 = (const float*)d_in[8];
  const float* D2 = (const float*)d_in[9];
  const float* c2 = (const float*)d_in[10];
  const float* D3 = (const float*)d_in[11];
  const float* c3 = (const float*)d_in[12];

  // ws: [0,64K) bf16 W1 | [64K,128K) fp8 W2 | [128K,192K) fp8 W3 |
  //     [384K,416K) msum
  uint8_t* pW   = (uint8_t*)d_ws;
  float*   msum = (float*)((char*)d_ws + 384 * 1024);

  pack_weights<<<640, 256, 0, stream>>>(W1, W2, W3, c3, pW, msum,
                                        (float*)d_out);
  encoder<<<NBLK, 512, 0, stream>>>(x, pW, b1, b2, b3, msum);
  decoder<<<256, 1024, 0, stream>>>(msum, D1, c1, D2, c2, D3,
                                    (float*)d_out);
}